// Round 1
// baseline (1024.688 us; speedup 1.0000x reference)
//
#include <hip/hip_runtime.h>
#include <hip/hip_bf16.h>
#include <cmath>

#define USER_NUM 52643
#define ITEM_NUM 91599
#define NNODE (USER_NUM + ITEM_NUM)   // 144242
#define DDIM 64

// ---------------- small utility kernels ----------------

__global__ void zero_ints_kernel(int* __restrict__ p, int n) {
    int i = blockIdx.x * 256 + threadIdx.x;
    if (i < n) p[i] = 0;
}

__global__ void init_loss_kernel(float* __restrict__ out, int loss_idx) {
    if (threadIdx.x == 0) out[loss_idx] = 0.0f;
}

// ---------------- CSR build ----------------

__global__ void hist_kernel(const int* __restrict__ rows, int* __restrict__ deg, int E) {
    int e = blockIdx.x * 256 + threadIdx.x;
    if (e < E) atomicAdd(&deg[rows[e]], 1);
}

// per-block (2048 elems) sums
__global__ void block_sums_kernel(const int* __restrict__ deg, int* __restrict__ bsums, int n) {
    int t = threadIdx.x;                 // 1024 threads
    int base = blockIdx.x * 2048;
    int s = 0;
    for (int i = t; i < 2048; i += 1024) {
        int idx = base + i;
        if (idx < n) s += deg[idx];
    }
    for (int off = 32; off; off >>= 1) s += __shfl_xor(s, off);
    __shared__ int ws[16];
    int lane = t & 63, wid = t >> 6;
    if (lane == 0) ws[wid] = s;
    __syncthreads();
    if (t < 64) {
        int v = (t < 16) ? ws[t] : 0;
        for (int off = 32; off; off >>= 1) v += __shfl_xor(v, off);
        if (t == 0) bsums[blockIdx.x] = v;
    }
}

__global__ void scan_bsums_kernel(int* __restrict__ bsums, int nb) {
    if (threadIdx.x == 0 && blockIdx.x == 0) {
        int acc = 0;
        for (int i = 0; i < nb; ++i) { int v = bsums[i]; bsums[i] = acc; acc += v; }
    }
}

// exclusive scan -> row_ptr (row_ptr[0]=0, row_ptr[i+1]=incl prefix)
__global__ void block_scan_kernel(const int* __restrict__ deg, const int* __restrict__ bsums,
                                  int* __restrict__ row_ptr, int n) {
    int t = threadIdx.x;                  // 1024 threads, 2 elems each
    int lane = t & 63, wid = t >> 6;
    int base = blockIdx.x * 2048;
    int i0 = base + 2 * t, i1 = i0 + 1;
    int d0 = (i0 < n) ? deg[i0] : 0;
    int d1 = (i1 < n) ? deg[i1] : 0;
    int s = d0 + d1;
    int v = s;
    #pragma unroll
    for (int delta = 1; delta < 64; delta <<= 1) {
        int src = lane - delta;
        int tmp = __shfl(v, (src < 0) ? lane : src);
        v += (src < 0) ? 0 : tmp;
    }
    __shared__ int wsum[16];
    __shared__ int woff[16];
    if (lane == 63) wsum[wid] = v;
    __syncthreads();
    if (t < 64) {
        int orig = (t < 16) ? wsum[t] : 0;
        int w = orig;
        #pragma unroll
        for (int delta = 1; delta < 64; delta <<= 1) {
            int src = t - delta;
            int tmp = __shfl(w, (src < 0) ? t : src);
            w += (src < 0) ? 0 : tmp;
        }
        if (t < 16) woff[t] = w - orig;   // exclusive
    }
    __syncthreads();
    int off = bsums[blockIdx.x] + woff[wid];
    int excl = off + v - s;               // exclusive prefix for this pair
    if (i0 < n) row_ptr[i0 + 1] = excl + d0;
    if (i1 < n) row_ptr[i1 + 1] = excl + d0 + d1;
    if (blockIdx.x == 0 && t == 0) row_ptr[0] = 0;
}

__global__ void scatter_kernel(const int* __restrict__ rows, const int* __restrict__ cols,
                               const float* __restrict__ vals, const int* __restrict__ row_ptr,
                               int* __restrict__ cnt, int* __restrict__ ccol,
                               float* __restrict__ cval, int E) {
    int e = blockIdx.x * 256 + threadIdx.x;
    if (e < E) {
        int r = rows[e];
        int pos = row_ptr[r] + atomicAdd(&cnt[r], 1);
        ccol[pos] = cols[e];
        cval[pos] = vals[e];
    }
}

// ---------------- fused GNN layer: SpMM(x), SpMM(x*x), 2x GEMM(64x64), bias, ReLU ----------------
// wave-per-row; lane = feature dim. SPLIT=1: x comes from two tables (user/item).

template <int SPLIT>
__global__ __launch_bounds__(256) void gnn_layer_kernel(
    const float* __restrict__ xA, const float* __restrict__ xB,
    const int* __restrict__ row_ptr, const int* __restrict__ ccol, const float* __restrict__ cval,
    const float* __restrict__ W, const float* __restrict__ b,
    const float* __restrict__ Wi, const float* __restrict__ bi,
    float* __restrict__ out)
{
    __shared__ float Wt[64 * 65];    // Wt[k*65+j] = W[j*64+k]
    __shared__ float Wit[64 * 65];
    int tid = threadIdx.x;
    int lane = tid & 63;
    int wid = tid >> 6;

    for (int i = tid; i < 64 * 64; i += 256) {
        int r = i >> 6, c = i & 63;          // W[r][c]
        Wt[c * 65 + r] = W[i];
        Wit[c * 65 + r] = Wi[i];
    }
    __syncthreads();

    int row = blockIdx.x * 4 + wid;
    if (row >= NNODE) return;

    int e0 = row_ptr[row], e1 = row_ptr[row + 1];
    float acc1 = 0.0f, acc2 = 0.0f;

    for (int base = e0; base < e1; base += 64) {
        int e = base + lane;
        int c = 0; float v = 0.0f;
        if (e < e1) { c = ccol[e]; v = cval[e]; }
        int nn = min(64, e1 - base);
        for (int i = 0; i < nn; i += 4) {
            float xv[4], vv[4];
            #pragma unroll
            for (int u = 0; u < 4; ++u) {
                int cc = __shfl(c, i + u);
                vv[u] = __shfl(v, i + u);
                const float* xp;
                if (SPLIT) xp = (cc < USER_NUM) ? (xA + (size_t)cc * DDIM)
                                                : (xB + (size_t)(cc - USER_NUM) * DDIM);
                else       xp = xA + (size_t)cc * DDIM;
                xv[u] = xp[lane];
            }
            #pragma unroll
            for (int u = 0; u < 4; ++u) {
                acc1 = fmaf(vv[u], xv[u], acc1);
                acc2 = fmaf(vv[u], xv[u] * xv[u], acc2);
            }
        }
    }

    float xr;
    if (SPLIT) xr = (row < USER_NUM) ? xA[(size_t)row * DDIM + lane]
                                     : xB[(size_t)(row - USER_NUM) * DDIM + lane];
    else       xr = xA[(size_t)row * DDIM + lane];
    float p1 = acc1 + xr;    // (L + I) @ x
    float p2 = acc2;         // L @ (x*x)

    float oj = b[lane] + bi[lane];
    #pragma unroll
    for (int k = 0; k < 64; ++k) {
        float s1 = __shfl(p1, k);
        float s2 = __shfl(p2, k);
        oj = fmaf(s1, Wt[k * 65 + lane], oj);
        oj = fmaf(s2, Wit[k * 65 + lane], oj);
    }
    out[(size_t)row * DDIM + lane] = fmaxf(oj, 0.0f);
}

// ---------------- scoring + loss ----------------

__global__ void score_kernel(const int* __restrict__ user, const int* __restrict__ item_i,
                             const int* __restrict__ item_j,
                             const float* __restrict__ eu, const float* __restrict__ ei,
                             const float* __restrict__ g1, const float* __restrict__ g2,
                             float* __restrict__ out, int B)
{
    int t = blockIdx.x * 256 + threadIdx.x;
    int w = t >> 6;
    int lane = t & 63;
    if (w >= B) return;

    int u  = user[w];
    int i0 = item_i[w];
    int j0 = item_j[w];
    int ii = USER_NUM + i0;
    int jj = USER_NUM + j0;

    float e0u = eu[(size_t)u  * DDIM + lane];
    float e0i = ei[(size_t)i0 * DDIM + lane];
    float e0j = ei[(size_t)j0 * DDIM + lane];
    float g1u = g1[(size_t)u  * DDIM + lane];
    float g1i = g1[(size_t)ii * DDIM + lane];
    float g1j = g1[(size_t)jj * DDIM + lane];
    float g2u = g2[(size_t)u  * DDIM + lane];
    float g2i = g2[(size_t)ii * DDIM + lane];
    float g2j = g2[(size_t)jj * DDIM + lane];

    float di = e0u * e0i + g1u * g1i + g2u * g2i;
    float dj = e0u * e0j + g1u * g1j + g2u * g2j;
    for (int off = 32; off; off >>= 1) {
        di += __shfl_xor(di, off);
        dj += __shfl_xor(dj, off);
    }
    if (lane == 0) {
        out[w] = di;
        out[B + w] = dj;
        float x = di - dj;
        // -log_sigmoid(x) = softplus(-x), stable
        float sp = fmaxf(-x, 0.0f) + log1pf(expf(-fabsf(x)));
        atomicAdd(&out[2 * B], sp);
    }
}

// ---------------- launch ----------------

extern "C" void kernel_launch(void* const* d_in, const int* in_sizes, int n_in,
                              void* d_out, int out_size, void* d_ws, size_t ws_size,
                              hipStream_t stream) {
    const int*   user       = (const int*)d_in[0];
    const int*   item_i     = (const int*)d_in[1];
    const int*   item_j     = (const int*)d_in[2];
    const int*   rows       = (const int*)d_in[3];
    const int*   cols       = (const int*)d_in[4];
    const float* vals       = (const float*)d_in[5];
    const float* embed_user = (const float*)d_in[6];
    const float* embed_item = (const float*)d_in[7];
    const float* W1  = (const float*)d_in[8];
    const float* b1  = (const float*)d_in[9];
    const float* Wi1 = (const float*)d_in[10];
    const float* bi1 = (const float*)d_in[11];
    const float* W2  = (const float*)d_in[12];
    const float* b2  = (const float*)d_in[13];
    const float* Wi2 = (const float*)d_in[14];
    const float* bi2 = (const float*)d_in[15];

    int B = in_sizes[0];
    int E = in_sizes[3];
    float* out = (float*)d_out;

    char* ws = (char*)d_ws;
    size_t off = 0;
    auto alloc = [&](size_t bytes) -> void* {
        void* p = ws + off;
        off += (bytes + 255) & ~(size_t)255;
        return p;
    };
    float* g1      = (float*)alloc((size_t)NNODE * DDIM * 4);
    float* g2      = (float*)alloc((size_t)NNODE * DDIM * 4);
    int*   row_ptr = (int*)alloc((size_t)(NNODE + 1) * 4);
    int*   deg     = (int*)alloc((size_t)NNODE * 4);       // reused as cnt
    int*   bsums   = (int*)alloc(4096);
    int*   ccol    = (int*)alloc((size_t)E * 4);
    float* cval    = (float*)alloc((size_t)E * 4);

    const int NB = (NNODE + 2047) / 2048;   // 71

    zero_ints_kernel<<<(NNODE + 255) / 256, 256, 0, stream>>>(deg, NNODE);
    hist_kernel<<<(E + 255) / 256, 256, 0, stream>>>(rows, deg, E);
    block_sums_kernel<<<NB, 1024, 0, stream>>>(deg, bsums, NNODE);
    scan_bsums_kernel<<<1, 64, 0, stream>>>(bsums, NB);
    block_scan_kernel<<<NB, 1024, 0, stream>>>(deg, bsums, row_ptr, NNODE);
    zero_ints_kernel<<<(NNODE + 255) / 256, 256, 0, stream>>>(deg, NNODE);
    scatter_kernel<<<(E + 255) / 256, 256, 0, stream>>>(rows, cols, vals, row_ptr, deg, ccol, cval, E);

    gnn_layer_kernel<1><<<(NNODE + 3) / 4, 256, 0, stream>>>(
        embed_user, embed_item, row_ptr, ccol, cval, W1, b1, Wi1, bi1, g1);
    gnn_layer_kernel<0><<<(NNODE + 3) / 4, 256, 0, stream>>>(
        g1, nullptr, row_ptr, ccol, cval, W2, b2, Wi2, bi2, g2);

    init_loss_kernel<<<1, 64, 0, stream>>>(out, 2 * B);
    score_kernel<<<(B * 64 + 255) / 256, 256, 0, stream>>>(
        user, item_i, item_j, embed_user, embed_item, g1, g2, out, B);
}